// Round 7
// baseline (315.549 us; speedup 1.0000x reference)
//
#include <hip/hip_runtime.h>

typedef _Float16 f16;
typedef _Float16 half8 __attribute__((ext_vector_type(8)));
typedef _Float16 f16x2 __attribute__((ext_vector_type(2)));
typedef float f32x4 __attribute__((ext_vector_type(4)));
typedef int i32x4 __attribute__((ext_vector_type(4)));
typedef unsigned short ushort_t;

// B=16, C=64, H=W=128, OUT=64, HW=16384

// ---------------- x NCHW fp32 -> xT NHWC f16, plus weight packing ----------------
// Blocks [0,2048): transpose. Blocks [2048,2112): pack weights -> [tap][oc][ic] f16.
__global__ __launch_bounds__(256) void transpose_pack_k(
    const float* __restrict__ x, f16* __restrict__ xT,
    const float* __restrict__ w_off, const float* __restrict__ w_conv,
    f16* __restrict__ W1p, f16* __restrict__ W2p)
{
    __shared__ float lds[64 * 132];
    const int tid = threadIdx.x;
    if (blockIdx.x >= 2048) {
        for (int t = (blockIdx.x - 2048) * 256 + tid; t < 110592; t += 16384) {
            if (t < 73728) {
                int tap = t >> 13, oc = (t >> 6) & 127, ic = t & 63;
                W1p[t] = (f16)w_off[(oc * 64 + ic) * 9 + tap];
            } else {
                int t2 = t - 73728;
                int tap = t2 >> 12, oc = (t2 >> 6) & 63, ic = t2 & 63;
                W2p[t2] = (f16)w_conv[(oc * 64 + ic) * 9 + tap];
            }
        }
        return;
    }
    const int b = blockIdx.x >> 7, h = blockIdx.x & 127;
    const float4* x4 = (const float4*)x;
    for (int i = tid; i < 2048; i += 256) {
        int ic = i >> 5, wq = i & 31;
        float4 v = x4[(b * 64 + ic) * 4096 + h * 32 + wq];
        *(float4*)&lds[ic * 132 + wq * 4] = v;
    }
    __syncthreads();
    for (int i = tid; i < 1024; i += 256) {
        int w = i & 127, kg = i >> 7;
        half8 hv;
        #pragma unroll
        for (int j = 0; j < 8; ++j) hv[j] = (f16)lds[(kg * 8 + j) * 132 + w];
        *(half8*)&xT[(((size_t)(b * 128 + h) * 128 + w) << 6) + kg * 8] = hv;
    }
}

__device__ __forceinline__ float bilin(const float* __restrict__ xp, float rr, float cc) {
    rr = fminf(fmaxf(rr, 0.f), 127.f);
    cc = fminf(fmaxf(cc, 0.f), 127.f);
    const float r0f = floorf(rr), c0f = floorf(cc);
    const float r1f = ceilf(rr),  c1f = ceilf(cc);
    const int r0 = (int)r0f, r1 = (int)r1f, c0 = (int)c0f, c1 = (int)c1f;
    const float v_lt = xp[(r0 << 7) + c0];
    const float v_rt = xp[(r1 << 7) + c0];
    const float v_lb = xp[(r0 << 7) + c1];
    const float v_rb = xp[(r1 << 7) + c1];
    const float fr = rr - r0f, fc = cc - c0f;
    const float vt = fr * (v_rt - v_lt) + v_lt;
    const float vb = fr * (v_rb - v_lb) + v_lb;
    return fc * (vb - vt) + vt;
}

// ---------------- fused conv1 (implicit GEMM, half src row) + deform gather ----
// Block (sr, ph, b): conv1 output row sr, src pixels [64ph, 64ph+64), all 128 oc.
// With t=sr>>1, u=sr&1: serves deform outputs h_out in {t, t+64},
// w_out = u*64 + w_off with w_off in [32ph, 32ph+32), all 64 channels.
// (deform (b,c,h_out,w_out) reads conv1 ch 2c+hsel at src row 2t+u = sr,
//  src cols 2*(w_out&63) + {0,1} — verified reshape derivation.)
// LDS phase 1: x tile [3 rows][66 cols][64 ic] f16, XOR-swizzled (25344 B).
// LDS phase 2 (reuse): cres[pix 0..63][ch 0..127] ushort, pitch 130 (16640 B).
__global__ __launch_bounds__(256, 4) void conv1_deform_k(
    const f16* __restrict__ xT, const float* __restrict__ x,
    const f16* __restrict__ Wp, f16* __restrict__ mapped)
{
    __shared__ char lds[25344];
    ushort_t* cres = (ushort_t*)lds;

    const int tid = threadIdx.x;
    const int sr = blockIdx.x >> 1, ph = blockIdx.x & 1;
    const int b = blockIdx.y;
    const int t = sr >> 1, u = sr & 1;
    const int col0 = ph * 64;

    // ---- stage xT rows sr-1..sr+1, cols col0-1..col0+64, swizzled ----
    {
        const i32x4* s4 = (const i32x4*)xT;
        for (int s = tid; s < 1584; s += 256) {       // 3*66*8 16B-slots
            int kg = s & 7, q = s >> 3;
            int c = q % 66, r = q / 66;
            int rowg = sr + r - 1, wg = col0 + c - 1;
            i32x4 v = {0, 0, 0, 0};
            if ((unsigned)rowg < 128u && (unsigned)wg < 128u)
                v = s4[((b * 128 + rowg) * 128 + wg) * 8 + kg];
            int off = (q << 7) + (kg << 4);
            off ^= (c & 7) << 4;
            *(i32x4*)(lds + off) = v;
        }
    }
    __syncthreads();

    const int lane = tid & 63, wv = tid >> 6;
    const int l15 = lane & 15, l4 = lane >> 4;
    const int ocb = wv * 32 + l15;      // wave owns 32 ocs x 64 pix

    f32x4 acc[2][4];
    #pragma unroll
    for (int m = 0; m < 2; ++m)
        #pragma unroll
        for (int n = 0; n < 4; ++n) acc[m][n] = {0.f, 0.f, 0.f, 0.f};

    half8 a_cur[2], a_nxt[2];
    #pragma unroll
    for (int m = 0; m < 2; ++m)
        a_cur[m] = *(const half8*)&Wp[(0 * 128 + ocb + m * 16) * 64 + l4 * 8];

    #pragma unroll
    for (int step = 0; step < 18; ++step) {
        const int tap = step >> 1, ks = step & 1;
        const int ky = tap / 3, kx = tap % 3;
        if (step < 17) {
            const int tap1 = (step + 1) >> 1, ks1 = (step + 1) & 1;
            #pragma unroll
            for (int m = 0; m < 2; ++m)
                a_nxt[m] = *(const half8*)&Wp[(tap1 * 128 + ocb + m * 16) * 64 + ks1 * 32 + l4 * 8];
        }
        #pragma unroll
        for (int n = 0; n < 4; ++n) {
            const int c = n * 16 + l15 + kx;          // halo col 0..65
            int off = ((ky * 66 + c) << 7) + (ks << 6) + (l4 << 4);
            off ^= (c & 7) << 4;
            const half8 bf = *(const half8*)(lds + off);
            acc[0][n] = __builtin_amdgcn_mfma_f32_16x16x32_f16(a_cur[0], bf, acc[0][n], 0, 0, 0);
            acc[1][n] = __builtin_amdgcn_mfma_f32_16x16x32_f16(a_cur[1], bf, acc[1][n], 0, 0, 0);
        }
        #pragma unroll
        for (int m = 0; m < 2; ++m) a_cur[m] = a_nxt[m];
    }

    __syncthreads();   // x tile dead; reuse LDS for conv1 results

    // ---- park conv1 half-row as f16: cres[pix_local][ch], pitch 130 ----
    // C/D layout: col(pix within 16) = l15, row(oc within 16) = l4*4 + i.
    #pragma unroll
    for (int m = 0; m < 2; ++m) {
        const int oc0 = wv * 32 + m * 16 + l4 * 4;
        #pragma unroll
        for (int n = 0; n < 4; ++n) {
            const int pix = n * 16 + l15;
            const int base = pix * 130 + oc0;
            f16x2 p0; p0[0] = (f16)acc[m][n][0]; p0[1] = (f16)acc[m][n][1];
            f16x2 p1; p1[0] = (f16)acc[m][n][2]; p1[1] = (f16)acc[m][n][3];
            *(f16x2*)&cres[base]     = p0;
            *(f16x2*)&cres[base + 2] = p1;
        }
    }
    __syncthreads();

    // ---- gather: thread -> (ch-group, hsel, w_rel) ----
    {
        const int w_rel = tid & 31;            // w_off = 32*ph + w_rel
        const int hsel = (tid >> 5) & 1;       // 0: h_out=t (ch 2c); 1: h_out=t+64 (ch 2c+1)
        const int cg = tid >> 6;               // 16 channels each
        const int w_out = u * 64 + 32 * ph + w_rel;
        const int h_out = t + hsel * 64;
        const int q = 2 * w_rel;               // local src pixel
        const float hb = (float)h_out, wb = (float)w_out;
        f16* mp = mapped + ((((size_t)b << 14) + h_out * 128 + w_out) << 6) + cg * 16;

        #pragma unroll
        for (int j = 0; j < 2; ++j) {
            half8 ov;
            #pragma unroll
            for (int e = 0; e < 8; ++e) {
                const int c = cg * 16 + j * 8 + e;
                const float R  = (float)*(const f16*)&cres[q * 130 + 2 * c + hsel];
                const float Cf = (float)*(const f16*)&cres[(q + 1) * 130 + 2 * c + hsel];
                const float* xp = x + (((size_t)b * 64 + c) << 14);
                ov[e] = (f16)bilin(xp, R + hb, Cf + wb);
            }
            *(half8*)&mp[j * 8] = ov;
        }
    }
}

// ---------------- conv2: implicit GEMM, half output row per block ----------------
// src: mapped NHWC f16. Wp: [9][64][64]. out: NCHW fp32 + bias.
__global__ __launch_bounds__(256, 6) void conv2_k(
    const f16* __restrict__ src, const f16* __restrict__ Wp,
    const float* __restrict__ bias, float* __restrict__ out)
{
    __shared__ char lds[25344];
    const int tid = threadIdx.x;
    const int h = blockIdx.x >> 1, ph = blockIdx.x & 1;
    const int b = blockIdx.y;
    const int col0 = ph * 64;

    {
        const i32x4* s4 = (const i32x4*)src;
        for (int s = tid; s < 1584; s += 256) {
            int kg = s & 7, q = s >> 3;
            int c = q % 66, r = q / 66;
            int rowg = h + r - 1, wg = col0 + c - 1;
            i32x4 v = {0, 0, 0, 0};
            if ((unsigned)rowg < 128u && (unsigned)wg < 128u)
                v = s4[((b * 128 + rowg) * 128 + wg) * 8 + kg];
            int off = (q << 7) + (kg << 4);
            off ^= (c & 7) << 4;
            *(i32x4*)(lds + off) = v;
        }
    }
    __syncthreads();

    const int lane = tid & 63, wv = tid >> 6;
    const int l15 = lane & 15, l4 = lane >> 4;
    const int wm = wv >> 1, wn = wv & 1;     // wave: 32 oc x 32 pix
    const int ocb = wm * 32 + l15;
    const int pixb = wn * 32;

    f32x4 acc[2][2];
    #pragma unroll
    for (int m = 0; m < 2; ++m)
        #pragma unroll
        for (int n = 0; n < 2; ++n) acc[m][n] = {0.f, 0.f, 0.f, 0.f};

    half8 a_cur[2], a_nxt[2];
    #pragma unroll
    for (int m = 0; m < 2; ++m)
        a_cur[m] = *(const half8*)&Wp[(0 * 64 + ocb + m * 16) * 64 + l4 * 8];

    #pragma unroll
    for (int step = 0; step < 18; ++step) {
        const int tap = step >> 1, ks = step & 1;
        const int ky = tap / 3, kx = tap % 3;
        if (step < 17) {
            const int tap1 = (step + 1) >> 1, ks1 = (step + 1) & 1;
            #pragma unroll
            for (int m = 0; m < 2; ++m)
                a_nxt[m] = *(const half8*)&Wp[(tap1 * 64 + ocb + m * 16) * 64 + ks1 * 32 + l4 * 8];
        }
        #pragma unroll
        for (int n = 0; n < 2; ++n) {
            const int c = pixb + n * 16 + l15 + kx;   // halo col 0..65
            int off = ((ky * 66 + c) << 7) + (ks << 6) + (l4 << 4);
            off ^= (c & 7) << 4;
            const half8 bf = *(const half8*)(lds + off);
            acc[0][n] = __builtin_amdgcn_mfma_f32_16x16x32_f16(a_cur[0], bf, acc[0][n], 0, 0, 0);
            acc[1][n] = __builtin_amdgcn_mfma_f32_16x16x32_f16(a_cur[1], bf, acc[1][n], 0, 0, 0);
        }
        #pragma unroll
        for (int m = 0; m < 2; ++m) a_cur[m] = a_nxt[m];
    }

    #pragma unroll
    for (int m = 0; m < 2; ++m) {
        #pragma unroll
        for (int i = 0; i < 4; ++i) {
            const int oc = wm * 32 + m * 16 + l4 * 4 + i;
            const float bb = bias[oc];
            #pragma unroll
            for (int n = 0; n < 2; ++n) {
                const int pix = col0 + pixb + n * 16 + l15;
                out[(((size_t)b * 64 + oc) << 14) + h * 128 + pix] = acc[m][n][i] + bb;
            }
        }
    }
}

extern "C" void kernel_launch(void* const* d_in, const int* in_sizes, int n_in,
                              void* d_out, int out_size, void* d_ws, size_t ws_size,
                              hipStream_t stream) {
    const float* x      = (const float*)d_in[0];
    const float* w_off  = (const float*)d_in[1];
    const float* w_conv = (const float*)d_in[2];
    const float* b_conv = (const float*)d_in[3];
    float* out = (float*)d_out;

    char* ws = (char*)d_ws;
    f16* xT     = (f16*)ws;                          // 33,554,432 B
    f16* mapped = (f16*)(ws + 33554432);             // 33,554,432 B
    f16* W1p    = (f16*)(ws + 67108864);             // 147,456 B
    f16* W2p    = (f16*)(ws + 67108864 + 147456);    // 73,728 B

    transpose_pack_k<<<2112, 256, 0, stream>>>(x, xT, w_off, w_conv, W1p, W2p);
    conv1_deform_k<<<dim3(256, 16), 256, 0, stream>>>(xT, x, W1p, mapped);
    conv2_k<<<dim3(256, 16), 256, 0, stream>>>(mapped, W2p, b_conv, out);
}

// Round 8
// 282.212 us; speedup vs baseline: 1.1181x; 1.1181x over previous
//
#include <hip/hip_runtime.h>

typedef _Float16 f16;
typedef _Float16 half8 __attribute__((ext_vector_type(8)));
typedef _Float16 f16x2 __attribute__((ext_vector_type(2)));
typedef float f32x4 __attribute__((ext_vector_type(4)));
typedef int i32x4 __attribute__((ext_vector_type(4)));
typedef unsigned short ushort_t;

// B=16, C=64, H=W=128, OUT=64, HW=16384

// ---------------- x NCHW fp32 -> xT NHWC f16, plus weight packing ----------------
__global__ __launch_bounds__(256) void transpose_pack_k(
    const float* __restrict__ x, f16* __restrict__ xT,
    const float* __restrict__ w_off, const float* __restrict__ w_conv,
    f16* __restrict__ W1p, f16* __restrict__ W2p)
{
    __shared__ float lds[64 * 132];
    const int tid = threadIdx.x;
    if (blockIdx.x >= 2048) {
        for (int t = (blockIdx.x - 2048) * 256 + tid; t < 110592; t += 16384) {
            if (t < 73728) {
                int tap = t >> 13, oc = (t >> 6) & 127, ic = t & 63;
                W1p[t] = (f16)w_off[(oc * 64 + ic) * 9 + tap];
            } else {
                int t2 = t - 73728;
                int tap = t2 >> 12, oc = (t2 >> 6) & 63, ic = t2 & 63;
                W2p[t2] = (f16)w_conv[(oc * 64 + ic) * 9 + tap];
            }
        }
        return;
    }
    const int b = blockIdx.x >> 7, h = blockIdx.x & 127;
    const float4* x4 = (const float4*)x;
    for (int i = tid; i < 2048; i += 256) {
        int ic = i >> 5, wq = i & 31;
        float4 v = x4[(b * 64 + ic) * 4096 + h * 32 + wq];
        *(float4*)&lds[ic * 132 + wq * 4] = v;
    }
    __syncthreads();
    for (int i = tid; i < 1024; i += 256) {
        int w = i & 127, kg = i >> 7;
        half8 hv;
        #pragma unroll
        for (int j = 0; j < 8; ++j) hv[j] = (f16)lds[(kg * 8 + j) * 132 + w];
        *(half8*)&xT[(((size_t)(b * 128 + h) * 128 + w) << 6) + kg * 8] = hv;
    }
}

__device__ __forceinline__ float bilin(const float* __restrict__ xp, float rr, float cc) {
    rr = fminf(fmaxf(rr, 0.f), 127.f);
    cc = fminf(fmaxf(cc, 0.f), 127.f);
    const float r0f = floorf(rr), c0f = floorf(cc);
    const float r1f = ceilf(rr),  c1f = ceilf(cc);
    const int r0 = (int)r0f, r1 = (int)r1f, c0 = (int)c0f, c1 = (int)c1f;
    const float v_lt = xp[(r0 << 7) + c0];
    const float v_rt = xp[(r1 << 7) + c0];
    const float v_lb = xp[(r0 << 7) + c1];
    const float v_rb = xp[(r1 << 7) + c1];
    const float fr = rr - r0f, fc = cc - c0f;
    const float vt = fr * (v_rt - v_lt) + v_lt;
    const float vb = fr * (v_rb - v_lb) + v_lb;
    return fc * (vb - vt) + vt;
}

// gather for conv1 src row srp (512 threads). cres: [pix 0..127][ch], pitch 130.
// Mapping (verified r5): output (b,c,h_out,w_out) reads conv1 ch 2c+hsel at
// src row 2t+u, local cols 2*w_rel (row off) and 2*w_rel+1 (col off).
__device__ __forceinline__ void do_gather(
    const char* lds, const float* __restrict__ x, f16* __restrict__ mapped,
    int b, int srp, int tid)
{
    const ushort_t* cres = (const ushort_t*)(lds + 66560);
    const int t = srp >> 1, u = srp & 1;
    const int w_rel = tid & 63;
    const int hsel = (tid >> 6) & 1;
    const int cg = tid >> 7;               // 0..3, 16 channels each
    const int w_out = u * 64 + w_rel;
    const int h_out = t + hsel * 64;
    const int q = 2 * w_rel;
    const float hb = (float)h_out, wb = (float)w_out;
    f16* mp = mapped + ((((size_t)b << 14) + h_out * 128 + w_out) << 6) + cg * 16;

    #pragma unroll
    for (int jj = 0; jj < 2; ++jj) {
        half8 ov;
        #pragma unroll
        for (int e = 0; e < 8; ++e) {
            const int c = cg * 16 + jj * 8 + e;
            const float R  = (float)*(const f16*)&cres[q * 130 + 2 * c + hsel];
            const float Cf = (float)*(const f16*)&cres[(q + 1) * 130 + 2 * c + hsel];
            const float* xp = x + (((size_t)b * 64 + c) << 14);
            ov[e] = (f16)bilin(xp, R + hb, Cf + wb);
        }
        *(half8*)&mp[jj * 8] = ov;
    }
}

// ---------------- conv1+deform: persistent 8-row strip, pipelined ----------------
// Block (strip, b), 512 thr (8 waves). Per iter i (sr = strip*8+i):
//   [stage-load row sr+2 -> regs][GEMM(sr) from ring][stage ds_write]
//   [barrier A][gather(sr-1)][barrier B][park(sr)]
// LDS: x-ring 4 slots x 16640 B (row = 130 cols x 64 ic f16, XOR-swizzled),
//      cres 128x130 ushort (33280 B) at +66560. Total 99840 B -> 1 block/CU.
__global__ __launch_bounds__(512, 2) void conv1_deform_k(
    const f16* __restrict__ xT, const float* __restrict__ x,
    const f16* __restrict__ Wp, f16* __restrict__ mapped)
{
    __shared__ char lds[99840];
    const int tid = threadIdx.x;
    const int sr0 = blockIdx.x * 8;
    const int b = blockIdx.y;
    const i32x4* s4 = (const i32x4*)xT;

    // prologue: stage rows sr0-1..sr0+1 into ring slots
    for (int r = 0; r < 3; ++r) {
        const int g = sr0 - 1 + r;
        const int slotb = ((g + 4) & 3) * 16640;
        for (int s = tid; s < 1040; s += 512) {
            const int kg = s & 7, c = s >> 3, wg = c - 1;
            i32x4 v = {0, 0, 0, 0};
            if ((unsigned)g < 128u && (unsigned)wg < 128u)
                v = s4[((b * 128 + g) * 128 + wg) * 8 + kg];
            int off = slotb + (c << 7) + (kg << 4);
            off ^= (c & 7) << 4;
            *(i32x4*)(lds + off) = v;
        }
    }
    __syncthreads();

    const int lane = tid & 63, wv = tid >> 6;
    const int l15 = lane & 15, l4 = lane >> 4;
    const int wm = wv >> 1, wn = wv & 1;     // wave: 32 oc x 64 pix
    const int ocb = wm * 32 + l15;
    const int pixb = wn * 64;
    ushort_t* cres = (ushort_t*)(lds + 66560);

    for (int i = 0; i < 8; ++i) {
        const int sr = sr0 + i;
        const int g = sr + 2;

        // ---- stage-load row sr+2 into regs (latency hides under GEMM) ----
        i32x4 st0 = {0,0,0,0}, st1 = {0,0,0,0}, st2 = {0,0,0,0};
        if (i < 7 && (unsigned)g < 128u) {
            {
                const int s = tid, kg = s & 7, c = s >> 3, wg = c - 1;
                if ((unsigned)wg < 128u) st0 = s4[((b * 128 + g) * 128 + wg) * 8 + kg];
            }
            {
                const int s = tid + 512, kg = s & 7, c = s >> 3, wg = c - 1;
                if ((unsigned)wg < 128u) st1 = s4[((b * 128 + g) * 128 + wg) * 8 + kg];
            }
            if (tid < 16) {
                const int s = tid + 1024, kg = s & 7, c = s >> 3, wg = c - 1;
                if ((unsigned)wg < 128u) st2 = s4[((b * 128 + g) * 128 + wg) * 8 + kg];
            }
        }

        // ---- GEMM row sr (reads ring slots (sr-1..sr+1)&3) ----
        f32x4 acc[2][4];
        #pragma unroll
        for (int m = 0; m < 2; ++m)
            #pragma unroll
            for (int n = 0; n < 4; ++n) acc[m][n] = {0.f, 0.f, 0.f, 0.f};

        half8 ab[3][2];   // 2-step-deep A prefetch ring (static indices via full unroll)
        #pragma unroll
        for (int p = 0; p < 2; ++p)
            #pragma unroll
            for (int m = 0; m < 2; ++m)
                ab[p][m] = *(const half8*)&Wp[(0 * 128 + ocb + m * 16) * 64 + p * 32 + l4 * 8];

        #pragma unroll
        for (int step = 0; step < 18; ++step) {
            const int tap = step >> 1, ks = step & 1;
            const int ky = tap / 3, kx = tap % 3;
            if (step < 16) {
                const int s2 = step + 2, tap2 = s2 >> 1, ks2 = s2 & 1;
                #pragma unroll
                for (int m = 0; m < 2; ++m)
                    ab[s2 % 3][m] = *(const half8*)&Wp[(tap2 * 128 + ocb + m * 16) * 64 + ks2 * 32 + l4 * 8];
            }
            const int slotb = ((sr - 1 + ky + 4) & 3) * 16640;
            #pragma unroll
            for (int n = 0; n < 4; ++n) {
                const int c = pixb + n * 16 + l15 + kx;
                int off = slotb + (c << 7) + (ks << 6) + (l4 << 4);
                off ^= (c & 7) << 4;
                const half8 bf = *(const half8*)(lds + off);
                acc[0][n] = __builtin_amdgcn_mfma_f32_16x16x32_f16(ab[step % 3][0], bf, acc[0][n], 0, 0, 0);
                acc[1][n] = __builtin_amdgcn_mfma_f32_16x16x32_f16(ab[step % 3][1], bf, acc[1][n], 0, 0, 0);
            }
        }

        // ---- stage ds_write row sr+2 -> ring slot (sr+2)&3 (unread this iter) ----
        if (i < 7) {
            const int slotb = ((g + 4) & 3) * 16640;
            {
                const int s = tid, kg = s & 7, c = s >> 3;
                int off = slotb + (c << 7) + (kg << 4); off ^= (c & 7) << 4;
                *(i32x4*)(lds + off) = st0;
            }
            {
                const int s = tid + 512, kg = s & 7, c = s >> 3;
                int off = slotb + (c << 7) + (kg << 4); off ^= (c & 7) << 4;
                *(i32x4*)(lds + off) = st1;
            }
            if (tid < 16) {
                const int s = tid + 1024, kg = s & 7, c = s >> 3;
                int off = slotb + (c << 7) + (kg << 4); off ^= (c & 7) << 4;
                *(i32x4*)(lds + off) = st2;
            }
        }

        __syncthreads();                       // A: stage visible; cres(i-1) final
        if (i > 0) do_gather(lds, x, mapped, b, sr - 1, tid);
        __syncthreads();                       // B: gather done before repark

        // ---- park conv1 row sr as f16 into cres[pix][ch] ----
        #pragma unroll
        for (int m = 0; m < 2; ++m) {
            const int oc0 = wm * 32 + m * 16 + l4 * 4;
            #pragma unroll
            for (int n = 0; n < 4; ++n) {
                const int pix = pixb + n * 16 + l15;
                const int base = pix * 130 + oc0;
                f16x2 p0; p0[0] = (f16)acc[m][n][0]; p0[1] = (f16)acc[m][n][1];
                f16x2 p1; p1[0] = (f16)acc[m][n][2]; p1[1] = (f16)acc[m][n][3];
                *(f16x2*)&cres[base]     = p0;
                *(f16x2*)&cres[base + 2] = p1;
            }
        }
    }
    __syncthreads();
    do_gather(lds, x, mapped, b, sr0 + 7, tid);
}

// ---------------- conv2: persistent 4-row strip, pipelined ----------------
// Block (strip, b), 256 thr (4 waves), 2 blocks/CU. Per iter:
// [stage-load h+2][GEMM(h)][stage ds_write][store+bias][barrier]
__global__ __launch_bounds__(256, 2) void conv2_k(
    const f16* __restrict__ src, const f16* __restrict__ Wp,
    const float* __restrict__ bias, float* __restrict__ out)
{
    __shared__ char lds[66560];   // ring 4 x 16640
    const int tid = threadIdx.x;
    const int h0 = blockIdx.x * 4;
    const int b = blockIdx.y;
    const i32x4* s4 = (const i32x4*)src;

    for (int r = 0; r < 3; ++r) {
        const int g = h0 - 1 + r;
        const int slotb = ((g + 4) & 3) * 16640;
        for (int s = tid; s < 1040; s += 256) {
            const int kg = s & 7, c = s >> 3, wg = c - 1;
            i32x4 v = {0, 0, 0, 0};
            if ((unsigned)g < 128u && (unsigned)wg < 128u)
                v = s4[((b * 128 + g) * 128 + wg) * 8 + kg];
            int off = slotb + (c << 7) + (kg << 4);
            off ^= (c & 7) << 4;
            *(i32x4*)(lds + off) = v;
        }
    }
    __syncthreads();

    const int lane = tid & 63, wv = tid >> 6;
    const int l15 = lane & 15, l4 = lane >> 4;
    const int wm = wv >> 1, wn = wv & 1;     // wave: 32 oc x 64 pix
    const int ocb = wm * 32 + l15;
    const int pixb = wn * 64;

    for (int i = 0; i < 4; ++i) {
        const int h = h0 + i;
        const int g = h + 2;

        i32x4 st0 = {0,0,0,0}, st1 = {0,0,0,0}, st2 = {0,0,0,0}, st3 = {0,0,0,0}, st4 = {0,0,0,0};
        if (i < 3 && (unsigned)g < 128u) {
            {
                const int s = tid, kg = s & 7, c = s >> 3, wg = c - 1;
                if ((unsigned)wg < 128u) st0 = s4[((b * 128 + g) * 128 + wg) * 8 + kg];
            }
            {
                const int s = tid + 256, kg = s & 7, c = s >> 3, wg = c - 1;
                if ((unsigned)wg < 128u) st1 = s4[((b * 128 + g) * 128 + wg) * 8 + kg];
            }
            {
                const int s = tid + 512, kg = s & 7, c = s >> 3, wg = c - 1;
                if ((unsigned)wg < 128u) st2 = s4[((b * 128 + g) * 128 + wg) * 8 + kg];
            }
            {
                const int s = tid + 768, kg = s & 7, c = s >> 3, wg = c - 1;
                if ((unsigned)wg < 128u) st3 = s4[((b * 128 + g) * 128 + wg) * 8 + kg];
            }
            if (tid < 16) {
                const int s = tid + 1024, kg = s & 7, c = s >> 3, wg = c - 1;
                if ((unsigned)wg < 128u) st4 = s4[((b * 128 + g) * 128 + wg) * 8 + kg];
            }
        }

        f32x4 acc[2][4];
        #pragma unroll
        for (int m = 0; m < 2; ++m)
            #pragma unroll
            for (int n = 0; n < 4; ++n) acc[m][n] = {0.f, 0.f, 0.f, 0.f};

        half8 ab[3][2];
        #pragma unroll
        for (int p = 0; p < 2; ++p)
            #pragma unroll
            for (int m = 0; m < 2; ++m)
                ab[p][m] = *(const half8*)&Wp[(0 * 64 + ocb + m * 16) * 64 + p * 32 + l4 * 8];

        #pragma unroll
        for (int step = 0; step < 18; ++step) {
            const int tap = step >> 1, ks = step & 1;
            const int ky = tap / 3, kx = tap % 3;
            if (step < 16) {
                const int s2 = step + 2, tap2 = s2 >> 1, ks2 = s2 & 1;
                #pragma unroll
                for (int m = 0; m < 2; ++m)
                    ab[s2 % 3][m] = *(const half8*)&Wp[(tap2 * 64 + ocb + m * 16) * 64 + ks2 * 32 + l4 * 8];
            }
            const int slotb = ((h - 1 + ky + 4) & 3) * 16640;
            #pragma unroll
            for (int n = 0; n < 4; ++n) {
                const int c = pixb + n * 16 + l15 + kx;
                int off = slotb + (c << 7) + (ks << 6) + (l4 << 4);
                off ^= (c & 7) << 4;
                const half8 bf = *(const half8*)(lds + off);
                acc[0][n] = __builtin_amdgcn_mfma_f32_16x16x32_f16(ab[step % 3][0], bf, acc[0][n], 0, 0, 0);
                acc[1][n] = __builtin_amdgcn_mfma_f32_16x16x32_f16(ab[step % 3][1], bf, acc[1][n], 0, 0, 0);
            }
        }

        if (i < 3) {
            const int slotb = ((g + 4) & 3) * 16640;
            {
                const int s = tid, kg = s & 7, c = s >> 3;
                int off = slotb + (c << 7) + (kg << 4); off ^= (c & 7) << 4;
                *(i32x4*)(lds + off) = st0;
            }
            {
                const int s = tid + 256, kg = s & 7, c = s >> 3;
                int off = slotb + (c << 7) + (kg << 4); off ^= (c & 7) << 4;
                *(i32x4*)(lds + off) = st1;
            }
            {
                const int s = tid + 512, kg = s & 7, c = s >> 3;
                int off = slotb + (c << 7) + (kg << 4); off ^= (c & 7) << 4;
                *(i32x4*)(lds + off) = st2;
            }
            {
                const int s = tid + 768, kg = s & 7, c = s >> 3;
                int off = slotb + (c << 7) + (kg << 4); off ^= (c & 7) << 4;
                *(i32x4*)(lds + off) = st3;
            }
            if (tid < 16) {
                const int s = tid + 1024, kg = s & 7, c = s >> 3;
                int off = slotb + (c << 7) + (kg << 4); off ^= (c & 7) << 4;
                *(i32x4*)(lds + off) = st4;
            }
        }

        // store output row h (+bias)
        #pragma unroll
        for (int m = 0; m < 2; ++m) {
            #pragma unroll
            for (int j = 0; j < 4; ++j) {
                const int oc = wm * 32 + m * 16 + l4 * 4 + j;
                const float bb = bias[oc];
                #pragma unroll
                for (int n = 0; n < 4; ++n) {
                    const int pix = pixb + n * 16 + l15;
                    out[(((size_t)b * 64 + oc) << 14) + h * 128 + pix] = acc[m][n][j] + bb;
                }
            }
        }

        __syncthreads();
    }
}

extern "C" void kernel_launch(void* const* d_in, const int* in_sizes, int n_in,
                              void* d_out, int out_size, void* d_ws, size_t ws_size,
                              hipStream_t stream) {
    const float* x      = (const float*)d_in[0];
    const float* w_off  = (const float*)d_in[1];
    const float* w_conv = (const float*)d_in[2];
    const float* b_conv = (const float*)d_in[3];
    float* out = (float*)d_out;

    char* ws = (char*)d_ws;
    f16* xT     = (f16*)ws;                          // 33,554,432 B
    f16* mapped = (f16*)(ws + 33554432);             // 33,554,432 B
    f16* W1p    = (f16*)(ws + 67108864);             // 147,456 B
    f16* W2p    = (f16*)(ws + 67108864 + 147456);    // 73,728 B

    transpose_pack_k<<<2112, 256, 0, stream>>>(x, xT, w_off, w_conv, W1p, W2p);
    conv1_deform_k<<<dim3(16, 16), 512, 0, stream>>>(xT, x, W1p, mapped);
    conv2_k<<<dim3(32, 16), 256, 0, stream>>>(mapped, W2p, b_conv, out);
}